// Round 11
// baseline (243.286 us; speedup 1.0000x reference)
//
#include <hip/hip_runtime.h>
#include <hip/hip_fp16.h>

// GCN 2-layer, N=100000, F=64, H=128, O=100, out [N,1] fp32.
// out = agg(relu(agg(x)@W1 + b1) . (W2@Wl)) + (b2@Wl + bl)
// r11: partB ELIMINATED. Degrees via global atomicAdd in partA (L2-resident);
// y emission is a standalone elementwise kernel; the 13-bin tile-sort happens
// inside fused1 phase-0 in LDS (bucket edges -> sbuf, gather loop reads LDS).
// Saves partB's 12.8MB csr rewrite+reread and a launch. out reads UNSORTED csr
// (zz = 400KB is L2-resident; sort order never mattered there).
// Cross-round facts baked in: fused1 is pinned at ~125K cycles by per-edge
// serialized cost (r5/r8/r10 all ~51us at 66/125/70MB fetch — duration
// invariant, rate inverse); BNODES=128 + tile-order keeps fetch ~70MB;
// fp32 LDS atomicAdd is a ~440cyc CAS loop (r1-r3) — int fixed-point ds_add
// everywhere; (tile,dl) sort makes same-address atomics (r9, reverted).
//  memset: deg[N]+bcur[1024] = 0.
//  partA:  blocks [0,nchunks): LDS multi-split into padded dst-buckets (ONE
//          reserve-atomic per bucket per block, staged run-length writes,
//          two-level scan) + deg[dst] global atomics. blocks [nchunks,+9):
//          prep (W1 fp16 hi+lo pack, v=W2@Wl, c=b2.Wl+bl, zero y-row).
//  y_kernel: dinv[i]=rsqrt(deg+1); y[i]=int16(x*dinv*2^12). Elementwise.
//  fused1: 782 blocks, 47KB LDS (3/CU); phase-0 in-LDS tile sort; tile-order
//          gather (8-edge x 8-int4-col, sched_barrier-pinned 8-deep); int16
//          sext -> native ds_add_u32 into stride-72 acci; MFMA + fused
//          layer-2-weight epilogue.
//  out:    per-bucket zz gather (L2-resident) + native int LDS accumulate.

#define N_NODES 100000
#define F_IN 64
#define HID 128
#define OUT2 100
#define BSHIFT 7
#define BNODES 128
#define NBUCKETS ((N_NODES + BNODES - 1) / BNODES)  // 782
#define SCAP 2560   // bucket capacity: mean 2046 + ~11 sigma
#define ACHUNK 4096 // edges per partA block
#define NB_PAD 1024
#define SENTB 0xFFFFu
#define SENTE 0xFFFFFFFFu
#define TSHIFT 13   // src tile = src >> 13 (8192 srcs = 1 MB of y per tile)
#define NTILES 13   // ceil(100000 / 8192)
#define RSTRIDE 72  // acci ints per node row: 8 cols x 9 (8 data + 1 pad)
#define ZROW N_NODES          // zero y-row for invalid gather slots
#define YSCALE 4096.0f        // y int16 fixed-point 2^12
#define YINV   (1.0f / 4096.0f)
#define ZSCALE 8192.0f        // zz accumulation fixed-point 2^13
#define ZINV   (1.0f / 8192.0f)

typedef _Float16 half8 __attribute__((ext_vector_type(8)));
typedef float f32x4 __attribute__((ext_vector_type(4)));

static __device__ __forceinline__ half8 as_half8(uint4 u) {
    union { uint4 u; half8 h; } x; x.u = u; return x.h;
}

// Pass A (+prep): edge blocks LDS-multisplit into padded dst-buckets and
// bump deg[dst]; prep blocks pack W1 / v / c / zero-row. bcur = per-bucket
// COUNTS (memset 0); reserve = b*SCAP + atomicAdd(count).
__global__ __launch_bounds__(256) void partA_kernel(
    const int* __restrict__ src, const int* __restrict__ dst,
    int* __restrict__ bcur, int* __restrict__ deg,
    unsigned int* __restrict__ ebuf, int E, int nchunks,
    const float* __restrict__ W1, const float* __restrict__ W2,
    const float* __restrict__ b2, const float* __restrict__ Wl,
    const float* __restrict__ bl,
    float* __restrict__ v, float* __restrict__ c, uint4* __restrict__ Wpk,
    int* __restrict__ yzero) {
    int t = threadIdx.x;
    if ((int)blockIdx.x >= nchunks) {
        int pb = (int)blockIdx.x - nchunks;
        if (pb < 8) {
            // idx: bit10 = part (0=hi,1=lo), bits9..7 = cb, bit6 = kf, bits5..0 = lane
            int idx = pb * 256 + t;
            int lane2 = idx & 63;
            int kf    = (idx >> 6) & 1;
            int cb    = (idx >> 7) & 7;
            int part  = (idx >> 10) & 1;
            union { uint4 u; unsigned short s[8]; } pk;
            #pragma unroll
            for (int j = 0; j < 8; ++j) {
                int k    = kf * 32 + (lane2 >> 4) * 8 + j;
                int colg = cb * 16 + (lane2 & 15);
                float w = W1[k * HID + colg];
                __half h = __float2half_rn(w);
                if (part) h = __float2half_rn(w - __half2float(h));
                pk.s[j] = __half_as_ushort(h);
            }
            Wpk[idx] = pk.u;
        } else {
            if (t < HID) {
                float acc = 0.f;
                for (int k = 0; k < OUT2; ++k) acc += W2[t * OUT2 + k] * Wl[k];
                v[t] = acc;
            } else if (t == HID) {
                float acc = bl[0];
                for (int k = 0; k < OUT2; ++k) acc += b2[k] * Wl[k];
                *c = acc;
            }
            if (t < 128) yzero[t] = 0;   // zero rows (int16) at y[N..]
        }
        return;
    }
    __shared__ unsigned int stage[ACHUNK];       // 16 KB
    __shared__ unsigned short sb[ACHUNK];        // 8 KB
    __shared__ int hist[NB_PAD];                 // 4 KB each
    __shared__ int ocnt[NB_PAD];
    __shared__ int gbase[NB_PAD];
    __shared__ int cnt2[NB_PAD];
    __shared__ int tsum[256];
    int base = blockIdx.x * ACHUNK;
    int total = E - base; if (total > ACHUNK) total = ACHUNK;

    #pragma unroll
    for (int i = 0; i < 4; ++i) { hist[t + i * 256] = 0; cnt2[t + i * 256] = 0; }
    __syncthreads();

    unsigned int pe[16];
    unsigned short bk[16];
    #pragma unroll
    for (int k = 0; k < 16; ++k) {
        int e = base + k * 256 + t;
        if (e < E) {
            int s = src[e], d = dst[e];
            pe[k] = ((unsigned int)s << BSHIFT) | (unsigned int)(d & (BNODES - 1));
            bk[k] = (unsigned short)(d >> BSHIFT);
            atomicAdd(&hist[bk[k]], 1);
            atomicAdd(&deg[d], 1);          // degree (L2-resident, low contention)
        } else {
            bk[k] = SENTB;
        }
    }
    __syncthreads();
    #pragma unroll
    for (int i = 0; i < 4; ++i) ocnt[t + i * 256] = hist[t + i * 256];
    __syncthreads();
    // two-level inclusive scan of hist[0..1023]: thread owns bins [4t,4t+4)
    int lcl[4];
    int s = 0;
    #pragma unroll
    for (int i = 0; i < 4; ++i) { s += hist[4 * t + i]; lcl[i] = s; }
    tsum[t] = s;
    __syncthreads();
    for (int off = 1; off < 256; off <<= 1) {
        int vv = (t >= off) ? tsum[t - off] : 0;
        __syncthreads();
        tsum[t] += vv;
        __syncthreads();
    }
    int cbase = tsum[t] - s;   // exclusive across thread chunks
    #pragma unroll
    for (int i = 0; i < 4; ++i) hist[4 * t + i] = cbase + lcl[i];  // inclusive
    __syncthreads();
    #pragma unroll
    for (int i = 0; i < 4; ++i) {
        int b = (t + i * 256 + blockIdx.x * 131) & (NB_PAD - 1);
        int cc = ocnt[b];
        if (cc > 0 && b < NBUCKETS)
            gbase[b] = b * SCAP + atomicAdd(&bcur[b], cc);
    }
    __syncthreads();
    #pragma unroll
    for (int k = 0; k < 16; ++k) {
        if (bk[k] != SENTB) {
            int b = bk[k];
            int pos = (hist[b] - ocnt[b]) + atomicAdd(&cnt2[b], 1);
            stage[pos] = pe[k];
            sb[pos] = (unsigned short)b;
        }
    }
    __syncthreads();
    #pragma unroll
    for (int k = 0; k < 16; ++k) {
        int idx = k * 256 + t;
        if (idx < total) {
            int b = sb[idx];
            int lo = hist[b] - ocnt[b];
            ebuf[gbase[b] + (idx - lo)] = stage[idx];
        }
    }
}

// Elementwise: dinv = rsqrt(deg+1); y = int16(x * dinv * 2^12).
__global__ __launch_bounds__(256) void y_kernel(
    const int* __restrict__ deg, float* __restrict__ dinv,
    const float4* __restrict__ x4, uint2* __restrict__ y2, int n) {
    int stride = gridDim.x * blockDim.x;
    for (int i = blockIdx.x * blockDim.x + threadIdx.x; i < n * 16; i += stride) {
        int node = i >> 4;
        float sd = rsqrtf((float)deg[node] + 1.0f);
        if ((i & 15) == 0) dinv[node] = sd;
        float sc = sd * YSCALE;
        float4 xv = x4[i];
        int a0 = __float2int_rn(xv.x * sc);
        int a1 = __float2int_rn(xv.y * sc);
        int a2 = __float2int_rn(xv.z * sc);
        int a3 = __float2int_rn(xv.w * sc);
        uint2 pk;
        pk.x = ((unsigned int)a0 & 0xFFFFu) | ((unsigned int)a1 << 16);
        pk.y = ((unsigned int)a2 & 0xFFFFu) | ((unsigned int)a3 << 16);
        y2[i] = pk;
    }
}

// Fused layer 1: block = bucket (128 dst nodes), 782 blocks, 47KB LDS (3/CU).
// Phase 0: in-LDS 13-bin tile sort of the bucket's edges (csr read once, no
// writeback). Main loop gathers in tile order from sbuf: live 1MB y-tile stays
// L2-hot per XCD (verified 66-70MB fetch r5/r10). 8-edge x 8-int4-col gather,
// sched_barrier keeps 8 loads in flight. int16 sext -> native ds_add_u32 into
// stride-72 acci. MFMA + fused layer-2-weight epilogue.
#define F1_ISSUE(EE, U, DL)                                            \
    _Pragma("unroll")                                                  \
    for (int g = 0; g < 8; ++g) {                                      \
        unsigned int e_ = __shfl((EE), g * 8 + q, 64);                 \
        int srow_ = (e_ != SENTE) ? (int)(e_ >> BSHIFT) : ZROW;        \
        DL[g] = (int)(e_ & (BNODES - 1));                              \
        U[g] = y4[srow_ * 8 + col];                                    \
    }

#define F1_CONSUME(U, DL)                                              \
    _Pragma("unroll")                                                  \
    for (int g = 0; g < 8; ++g) {                                      \
        int* rowp_ = &acci[DL[g] * RSTRIDE + col * 9];                 \
        const int* up_ = (const int*)&U[g];                            \
        _Pragma("unroll")                                              \
        for (int j = 0; j < 4; ++j) {                                  \
            int d_ = up_[j];                                           \
            atomicAdd(&rowp_[2 * j],     (d_ << 16) >> 16);            \
            atomicAdd(&rowp_[2 * j + 1], d_ >> 16);                    \
        }                                                              \
    }

__global__ __launch_bounds__(256, 3) void fused1_kernel(
    const int4* __restrict__ y4, const short* __restrict__ yh,
    const unsigned int* __restrict__ csr, const int* __restrict__ bcur,
    const float* __restrict__ dinv, const uint4* __restrict__ Wpk,
    const float* __restrict__ b1, const float* __restrict__ v,
    float* __restrict__ zz, int n) {
    __shared__ unsigned int sbuf[SCAP];      // 10 KB tile-sorted edges
    __shared__ int acci[BNODES * RSTRIDE];   // 36.9 KB accumulator
    __shared__ int tcnt[16];
    __shared__ int tcur[16];
    int t = threadIdx.x;
    int lane = t & 63, wave = t >> 6;
    int q = lane >> 3, col = lane & 7;
    int b = blockIdx.x;
    int node0 = b << BSHIFT;
    int nlocal = min(BNODES, n - node0);
    int base = b * SCAP;
    int cnt = bcur[b];
    if (cnt > SCAP) cnt = SCAP;

    if (t < 16) tcnt[t] = 0;
    __syncthreads();

    // phase 0a: load bucket edges to regs + tile histogram; overlap acci init
    unsigned int er[SCAP / 256];
    #pragma unroll
    for (int k = 0; k < SCAP / 256; ++k) {
        int idx = k * 256 + t;
        er[k] = (idx < cnt) ? csr[base + idx] : SENTE;
        if (er[k] != SENTE) atomicAdd(&tcnt[er[k] >> (BSHIFT + TSHIFT)], 1);
    }
    // self-loop init: acc[r][f] = y[node0+r][f] (int16, already dinv-prescaled)
    for (int r = wave; r < BNODES; r += 4) {
        int vv = 0;
        if (r < nlocal) vv = (int)yh[(node0 + r) * 64 + lane];
        acci[r * RSTRIDE + q * 9 + col] = vv;
    }
    __syncthreads();
    if (t == 0) {
        int s = 0;
        #pragma unroll
        for (int i = 0; i < NTILES; ++i) { tcur[i] = s; s += tcnt[i]; }
    }
    __syncthreads();
    // phase 0b: scatter to sbuf in tile order
    #pragma unroll
    for (int k = 0; k < SCAP / 256; ++k) {
        unsigned int e = er[k];
        if (e != SENTE) {
            int p = atomicAdd(&tcur[e >> (BSHIFT + TSHIFT)], 1);
            sbuf[p] = e;
        }
    }
    __syncthreads();

    // main: tile-order gather; per round each wave owns 64 edges from sbuf.
    int nr = (cnt + 255) >> 8;
    int lpos = wave * 64 + lane;
    for (int r = 0; r < nr; ++r) {
        int p = lpos + r * 256;
        unsigned int ee = (p < cnt) ? sbuf[p] : SENTE;
        int4 u[8]; int dl[8];
        F1_ISSUE(ee, u, dl);
        __builtin_amdgcn_sched_barrier(0);   // loads stay above: 8 in flight
        F1_CONSUME(u, dl);
    }
    __syncthreads();

    // MFMA + epilogue: each wave handles 2 sub-tiles of 16 nodes.
    int mm = lane & 15, kq = lane >> 4;
    for (int i = 0; i < 2; ++i) {
        int st = wave * 2 + i;
        int row = st * 16 + mm;
        float dis = ((row < nlocal) ? dinv[node0 + row] : 0.f) * YINV;
        const int* ap = &acci[row * RSTRIDE];
        half8 A0, A1;
        #pragma unroll
        for (int j = 0; j < 8; ++j) {
            A0[j] = (_Float16)(dis * (float)ap[kq * 9 + j]);
            A1[j] = (_Float16)(dis * (float)ap[(4 + kq) * 9 + j]);
        }
        f32x4 acc[8];
        #pragma unroll
        for (int cb = 0; cb < 8; ++cb) acc[cb] = (f32x4){0.f, 0.f, 0.f, 0.f};
        #pragma unroll
        for (int cb = 0; cb < 8; ++cb) {
            half8 bh0 = as_half8(Wpk[(cb * 2 + 0) * 64 + lane]);
            half8 bh1 = as_half8(Wpk[(cb * 2 + 1) * 64 + lane]);
            half8 bl0 = as_half8(Wpk[1024 + (cb * 2 + 0) * 64 + lane]);
            half8 bl1 = as_half8(Wpk[1024 + (cb * 2 + 1) * 64 + lane]);
            acc[cb] = __builtin_amdgcn_mfma_f32_16x16x32_f16(A0, bh0, acc[cb], 0, 0, 0);
            acc[cb] = __builtin_amdgcn_mfma_f32_16x16x32_f16(A1, bh1, acc[cb], 0, 0, 0);
            acc[cb] = __builtin_amdgcn_mfma_f32_16x16x32_f16(A0, bl0, acc[cb], 0, 0, 0);
            acc[cb] = __builtin_amdgcn_mfma_f32_16x16x32_f16(A1, bl1, acc[cb], 0, 0, 0);
        }
        float zp[4] = {0.f, 0.f, 0.f, 0.f};
        #pragma unroll
        for (int cb = 0; cb < 8; ++cb) {
            int colg = cb * 16 + mm;
            float bb1 = b1[colg], vv = v[colg];
            #pragma unroll
            for (int rr = 0; rr < 4; ++rr) {
                float h = acc[cb][rr] + bb1;
                h = fmaxf(h, 0.f);
                zp[rr] += h * vv;
            }
        }
        #pragma unroll
        for (int off = 1; off < 16; off <<= 1) {
            #pragma unroll
            for (int rr = 0; rr < 4; ++rr) zp[rr] += __shfl_xor(zp[rr], off, 64);
        }
        if (mm == 0) {
            int nb = st * 16 + kq * 4;
            #pragma unroll
            for (int rr = 0; rr < 4; ++rr)
                if (nb + rr < nlocal)
                    zz[node0 + nb + rr] = dinv[node0 + nb + rr] * zp[rr];
        }
    }
}

// Layer 2 (collapsed): per-bucket zz gather (zz = 400KB L2-resident) +
// native int LDS accumulate. out[i] = c + dinv[i]*(zz[i] + sum_in zz[s]).
__global__ __launch_bounds__(256) void out_kernel(
    const int* __restrict__ bcur, const unsigned int* __restrict__ csr,
    const float* __restrict__ dinv, const float* __restrict__ zz,
    const float* __restrict__ c, float* __restrict__ out, int n) {
    __shared__ int acc2[BNODES];
    int b = blockIdx.x, t = threadIdx.x;
    int node0 = b << BSHIFT;
    int nlocal = min(BNODES, n - node0);
    int base = b * SCAP;
    int cnt = bcur[b];
    if (cnt > SCAP) cnt = SCAP;
    if (t < BNODES) acc2[t] = 0;
    __syncthreads();
    for (int idx = t; idx < cnt; idx += 256) {
        unsigned int e = csr[base + idx];
        float z = zz[e >> BSHIFT];
        atomicAdd(&acc2[e & (BNODES - 1)], __float2int_rn(z * ZSCALE));
    }
    __syncthreads();
    if (t < nlocal) {
        int node = node0 + t;
        out[node] = c[0] + dinv[node] * ((float)acc2[t] * ZINV + zz[node]);
    }
}

extern "C" void kernel_launch(void* const* d_in, const int* in_sizes, int n_in,
                              void* d_out, int out_size, void* d_ws, size_t ws_size,
                              hipStream_t stream) {
    const float* x  = (const float*)d_in[0];
    const int*   ei = (const int*)d_in[1];
    const float* W1 = (const float*)d_in[2];
    const float* b1 = (const float*)d_in[3];
    const float* W2 = (const float*)d_in[4];
    const float* b2 = (const float*)d_in[5];
    const float* Wl = (const float*)d_in[6];
    const float* bl = (const float*)d_in[7];
    float* out = (float*)d_out;

    int E = in_sizes[1] / 2;
    const int* src = ei;
    const int* dst = ei + E;

    float* ws      = (float*)d_ws;
    int*   deg     = (int*)ws;                  // 100000 (memset w/ bcur)
    int*   bcur    = deg + N_NODES;             // 1024
    float* dinv    = (float*)(bcur + NB_PAD);   // 100000
    float* zz      = dinv + N_NODES;            // 100000
    float* v       = zz + N_NODES;              // 128
    float* c       = v + HID;                   // 4
    int*   csr     = (int*)(c + 4);             // NBUCKETS*SCAP = 2001920 ints
    uint4* Wpk     = (uint4*)(csr + (size_t)NBUCKETS * SCAP);  // 2048 uint4
    short* y       = (short*)((float*)Wpk + 8192);  // (N+4)*64 int16

    int nchunks = (E + ACHUNK - 1) / ACHUNK;   // 391

    hipMemsetAsync(deg, 0, (N_NODES + NB_PAD) * sizeof(int), stream);
    partA_kernel<<<nchunks + 9, 256, 0, stream>>>(
        src, dst, bcur, deg, (unsigned int*)csr, E, nchunks,
        W1, W2, b2, Wl, bl, v, c, Wpk, (int*)(y + (size_t)ZROW * 64));
    y_kernel<<<2048, 256, 0, stream>>>(
        deg, dinv, (const float4*)x, (uint2*)y, N_NODES);
    fused1_kernel<<<NBUCKETS, 256, 0, stream>>>(
        (const int4*)y, (const short*)y, (const unsigned int*)csr,
        bcur, dinv, Wpk, b1, v, zz, N_NODES);
    out_kernel<<<NBUCKETS, 256, 0, stream>>>(
        bcur, (const unsigned int*)csr, dinv, zz, c, out, N_NODES);
}

// Round 12
// 199.734 us; speedup vs baseline: 1.2180x; 1.2180x over previous
//
#include <hip/hip_runtime.h>
#include <hip/hip_fp16.h>

// GCN 2-layer, N=100000, F=64, H=128, O=100, out [N,1] fp32.
// out = agg(relu(agg(x)@W1 + b1) . (W2@Wl)) + (b2@Wl + bl)
// r12 = r10 minus dead machinery:
//  partA:  ACHUNK=2048, 782 edge-blocks (3/CU). hist -> per-bucket reserve ->
//          rank via cnt2 -> DIRECT scattered 4B store (stage/sb/1024-scan
//          DELETED — csr is 8MB, L2-resident, lines merge & write back once).
//          2 barriers instead of ~20. prep blocks ride along.
//  partB:  dl-hist -> dinv + int16 y emission ONLY (sort + 8MB csr writeback
//          DELETED; deg stays bucket-local — r11's global deg atomics cost
//          35us in cross-XCD line bouncing).
//  fused1: 13-bin tile sort in phase-0 LDS (~3 wave-instr per 64 edges, vs 64
//          for feature accumulation — measured nearly free in r11), then
//          tile-order gather (live 1MB y-tile L2-hot per XCD, ~70MB fetch),
//          8-edge x 8-int4-col, sched_barrier 8-deep; int16 sext -> native
//          ds_add_u32 into stride-72 acci; MFMA + fused L2-weight epilogue.
//  out:    per-bucket zz gather (unsorted csr; zz = 400KB L2-resident).
// Invariants: fp32 LDS atomicAdd = ~440cyc CAS (r1-r3) -> int fixed-point
// ds_add everywhere; (tile,dl) sort -> same-address atomics (r9, never);
// fused1 pinned ~125K cycles by per-edge serialized cost (r5/r8/r10).

#define N_NODES 100000
#define F_IN 64
#define HID 128
#define OUT2 100
#define BSHIFT 7
#define BNODES 128
#define NBUCKETS ((N_NODES + BNODES - 1) / BNODES)  // 782
#define SCAP 2560   // bucket capacity: mean 2046 + ~11 sigma
#define ACHUNK 2048 // edges per partA block (782 edge-blocks)
#define NB_PAD 1024
#define SENTE 0xFFFFFFFFu
#define TSHIFT 13   // src tile = src >> 13 (8192 srcs = 1 MB of y per tile)
#define NTILES 13   // ceil(100000 / 8192)
#define SCHUNK (SCAP / 256)   // 10
#define RSTRIDE 72  // acci ints per node row: 8 cols x 9 (8 data + 1 pad)
#define ZROW N_NODES          // zero y-row for invalid gather slots
#define YSCALE 4096.0f        // y int16 fixed-point 2^12
#define YINV   (1.0f / 4096.0f)
#define ZSCALE 8192.0f        // zz accumulation fixed-point 2^13
#define ZINV   (1.0f / 8192.0f)

typedef _Float16 half8 __attribute__((ext_vector_type(8)));
typedef float f32x4 __attribute__((ext_vector_type(4)));

static __device__ __forceinline__ half8 as_half8(uint4 u) {
    union { uint4 u; half8 h; } x; x.u = u; return x.h;
}

// Pass A (+prep): edge blocks: hist -> reserve -> direct scattered store.
// bcur = per-bucket COUNTS (memset 0); reserve = b*SCAP + atomicAdd(count).
__global__ __launch_bounds__(256) void partA_kernel(
    const int* __restrict__ src, const int* __restrict__ dst,
    int* __restrict__ bcur, unsigned int* __restrict__ ebuf, int E, int nchunks,
    const float* __restrict__ W1, const float* __restrict__ W2,
    const float* __restrict__ b2, const float* __restrict__ Wl,
    const float* __restrict__ bl,
    float* __restrict__ v, float* __restrict__ c, uint4* __restrict__ Wpk,
    int* __restrict__ yzero) {
    int t = threadIdx.x;
    if ((int)blockIdx.x >= nchunks) {
        int pb = (int)blockIdx.x - nchunks;
        if (pb < 8) {
            // idx: bit10 = part (0=hi,1=lo), bits9..7 = cb, bit6 = kf, bits5..0 = lane
            int idx = pb * 256 + t;
            int lane2 = idx & 63;
            int kf    = (idx >> 6) & 1;
            int cb    = (idx >> 7) & 7;
            int part  = (idx >> 10) & 1;
            union { uint4 u; unsigned short s[8]; } pk;
            #pragma unroll
            for (int j = 0; j < 8; ++j) {
                int k    = kf * 32 + (lane2 >> 4) * 8 + j;
                int colg = cb * 16 + (lane2 & 15);
                float w = W1[k * HID + colg];
                __half h = __float2half_rn(w);
                if (part) h = __float2half_rn(w - __half2float(h));
                pk.s[j] = __half_as_ushort(h);
            }
            Wpk[idx] = pk.u;
        } else {
            if (t < HID) {
                float acc = 0.f;
                for (int k = 0; k < OUT2; ++k) acc += W2[t * OUT2 + k] * Wl[k];
                v[t] = acc;
            } else if (t == HID) {
                float acc = bl[0];
                for (int k = 0; k < OUT2; ++k) acc += b2[k] * Wl[k];
                *c = acc;
            }
            if (t < 128) yzero[t] = 0;   // zero rows (int16) at y[N..]
        }
        return;
    }
    __shared__ int hist[NB_PAD];     // 4 KB
    __shared__ int gbase[NB_PAD];    // 4 KB
    __shared__ int cnt2[NB_PAD];     // 4 KB
    int base = blockIdx.x * ACHUNK;

    #pragma unroll
    for (int i = 0; i < 4; ++i) { hist[t + i * 256] = 0; cnt2[t + i * 256] = 0; }
    __syncthreads();

    unsigned int pe[8];
    int bk[8];
    #pragma unroll
    for (int k = 0; k < 8; ++k) {
        int e = base + k * 256 + t;
        if (e < E) {
            int s = src[e], d = dst[e];
            pe[k] = ((unsigned int)s << BSHIFT) | (unsigned int)(d & (BNODES - 1));
            bk[k] = d >> BSHIFT;
            atomicAdd(&hist[bk[k]], 1);
        } else {
            bk[k] = -1;
        }
    }
    __syncthreads();
    #pragma unroll
    for (int i = 0; i < 4; ++i) {
        int b = t + i * 256;
        int cc = hist[b];
        if (cc > 0 && b < NBUCKETS)
            gbase[b] = b * SCAP + atomicAdd(&bcur[b], cc);
    }
    __syncthreads();
    #pragma unroll
    for (int k = 0; k < 8; ++k) {
        if (bk[k] >= 0) {
            int b = bk[k];
            int rank = atomicAdd(&cnt2[b], 1);
            ebuf[gbase[b] + rank] = pe[k];   // direct 4B scatter; L2 merges lines
        }
    }
}

// Pass B: per bucket: dl-histogram -> dinv; int16 (2^12) pre-scaled y rows.
// No sort, no csr writeback.
__global__ __launch_bounds__(256) void partB_kernel(
    const int* __restrict__ bcur, const unsigned int* __restrict__ csr,
    float* __restrict__ dinv,
    const float4* __restrict__ x4, uint2* __restrict__ y2, int n) {
    __shared__ int lcnt[BNODES];
    __shared__ float sdinv[BNODES];
    int b = blockIdx.x, t = threadIdx.x;
    int node0 = b << BSHIFT;
    int nlocal = min(BNODES, n - node0);
    int base = b * SCAP;
    int cnt = bcur[b];
    if (cnt > SCAP) cnt = SCAP;
    if (t < BNODES) lcnt[t] = 0;
    __syncthreads();
    for (int idx = t; idx < cnt; idx += 256) {
        unsigned int e = csr[base + idx];
        atomicAdd(&lcnt[e & (BNODES - 1)], 1);
    }
    __syncthreads();
    if (t < BNODES) {
        float sd = rsqrtf((float)lcnt[t] + 1.0f);
        sdinv[t] = sd;
        if (t < nlocal) dinv[node0 + t] = sd;
    }
    __syncthreads();
    // y emission: int16 fixed-point, dinv[src]-prescaled
    for (int i = t; i < nlocal * 16; i += 256) {
        int nl = i >> 4;
        int gi = (node0 + nl) * 16 + (i & 15);
        float sc = sdinv[nl] * YSCALE;
        float4 xv = x4[gi];
        int a0 = __float2int_rn(xv.x * sc);
        int a1 = __float2int_rn(xv.y * sc);
        int a2 = __float2int_rn(xv.z * sc);
        int a3 = __float2int_rn(xv.w * sc);
        uint2 pk;
        pk.x = ((unsigned int)a0 & 0xFFFFu) | ((unsigned int)a1 << 16);
        pk.y = ((unsigned int)a2 & 0xFFFFu) | ((unsigned int)a3 << 16);
        y2[gi] = pk;
    }
}

// Fused layer 1: block = bucket (128 dst nodes), 782 blocks, ~47KB LDS (3/CU).
// Phase 0: in-LDS 13-bin tile sort (csr read once, no writeback; ~3 wave-instr
// per 64 edges). Main: tile-order gather from sbuf — live 1MB y-tile L2-hot
// per XCD. 8-edge x 8-int4-col, sched_barrier keeps 8 loads in flight. int16
// sext -> native ds_add_u32 into stride-72 acci. MFMA + fused L2-weight epi.
#define F1_ISSUE(EE, U, DL)                                            \
    _Pragma("unroll")                                                  \
    for (int g = 0; g < 8; ++g) {                                      \
        unsigned int e_ = __shfl((EE), g * 8 + q, 64);                 \
        int srow_ = (e_ != SENTE) ? (int)(e_ >> BSHIFT) : ZROW;        \
        DL[g] = (int)(e_ & (BNODES - 1));                              \
        U[g] = y4[srow_ * 8 + col];                                    \
    }

#define F1_CONSUME(U, DL)                                              \
    _Pragma("unroll")                                                  \
    for (int g = 0; g < 8; ++g) {                                      \
        int* rowp_ = &acci[DL[g] * RSTRIDE + col * 9];                 \
        const int* up_ = (const int*)&U[g];                            \
        _Pragma("unroll")                                              \
        for (int j = 0; j < 4; ++j) {                                  \
            int d_ = up_[j];                                           \
            atomicAdd(&rowp_[2 * j],     (d_ << 16) >> 16);            \
            atomicAdd(&rowp_[2 * j + 1], d_ >> 16);                    \
        }                                                              \
    }

__global__ __launch_bounds__(256, 3) void fused1_kernel(
    const int4* __restrict__ y4, const short* __restrict__ yh,
    const unsigned int* __restrict__ csr, const int* __restrict__ bcur,
    const float* __restrict__ dinv, const uint4* __restrict__ Wpk,
    const float* __restrict__ b1, const float* __restrict__ v,
    float* __restrict__ zz, int n) {
    __shared__ unsigned int sbuf[SCAP];      // 10.2 KB tile-sorted edges
    __shared__ int acci[BNODES * RSTRIDE];   // 36.9 KB accumulator
    __shared__ int tcnt[16];
    __shared__ int tcur[16];
    int t = threadIdx.x;
    int lane = t & 63, wave = t >> 6;
    int q = lane >> 3, col = lane & 7;
    int b = blockIdx.x;
    int node0 = b << BSHIFT;
    int nlocal = min(BNODES, n - node0);
    int base = b * SCAP;
    int cnt = bcur[b];
    if (cnt > SCAP) cnt = SCAP;

    if (t < 16) tcnt[t] = 0;
    __syncthreads();

    // phase 0a: bucket edges -> regs + tile histogram; overlap acci init
    unsigned int er[SCHUNK];
    #pragma unroll
    for (int k = 0; k < SCHUNK; ++k) {
        int idx = k * 256 + t;
        er[k] = (idx < cnt) ? csr[base + idx] : SENTE;
        if (er[k] != SENTE) atomicAdd(&tcnt[er[k] >> (BSHIFT + TSHIFT)], 1);
    }
    // self-loop init: acc[r][f] = y[node0+r][f] (int16, already dinv-prescaled)
    for (int r = wave; r < BNODES; r += 4) {
        int vv = 0;
        if (r < nlocal) vv = (int)yh[(node0 + r) * 64 + lane];
        acci[r * RSTRIDE + q * 9 + col] = vv;
    }
    __syncthreads();
    if (t == 0) {
        int s = 0;
        #pragma unroll
        for (int i = 0; i < NTILES; ++i) { tcur[i] = s; s += tcnt[i]; }
    }
    __syncthreads();
    // phase 0b: scatter to sbuf in tile order
    #pragma unroll
    for (int k = 0; k < SCHUNK; ++k) {
        unsigned int e = er[k];
        if (e != SENTE) {
            int p = atomicAdd(&tcur[e >> (BSHIFT + TSHIFT)], 1);
            sbuf[p] = e;
        }
    }
    __syncthreads();

    // main: tile-order gather; per round each wave owns 64 edges from sbuf.
    int nr = (cnt + 255) >> 8;
    int lpos = wave * 64 + lane;
    for (int r = 0; r < nr; ++r) {
        int p = lpos + r * 256;
        unsigned int ee = (p < cnt) ? sbuf[p] : SENTE;
        int4 u[8]; int dl[8];
        F1_ISSUE(ee, u, dl);
        __builtin_amdgcn_sched_barrier(0);   // loads stay above: 8 in flight
        F1_CONSUME(u, dl);
    }
    __syncthreads();

    // MFMA + epilogue: each wave handles 2 sub-tiles of 16 nodes.
    int mm = lane & 15, kq = lane >> 4;
    for (int i = 0; i < 2; ++i) {
        int st = wave * 2 + i;
        int row = st * 16 + mm;
        float dis = ((row < nlocal) ? dinv[node0 + row] : 0.f) * YINV;
        const int* ap = &acci[row * RSTRIDE];
        half8 A0, A1;
        #pragma unroll
        for (int j = 0; j < 8; ++j) {
            A0[j] = (_Float16)(dis * (float)ap[kq * 9 + j]);
            A1[j] = (_Float16)(dis * (float)ap[(4 + kq) * 9 + j]);
        }
        f32x4 acc[8];
        #pragma unroll
        for (int cb = 0; cb < 8; ++cb) acc[cb] = (f32x4){0.f, 0.f, 0.f, 0.f};
        #pragma unroll
        for (int cb = 0; cb < 8; ++cb) {
            half8 bh0 = as_half8(Wpk[(cb * 2 + 0) * 64 + lane]);
            half8 bh1 = as_half8(Wpk[(cb * 2 + 1) * 64 + lane]);
            half8 bl0 = as_half8(Wpk[1024 + (cb * 2 + 0) * 64 + lane]);
            half8 bl1 = as_half8(Wpk[1024 + (cb * 2 + 1) * 64 + lane]);
            acc[cb] = __builtin_amdgcn_mfma_f32_16x16x32_f16(A0, bh0, acc[cb], 0, 0, 0);
            acc[cb] = __builtin_amdgcn_mfma_f32_16x16x32_f16(A1, bh1, acc[cb], 0, 0, 0);
            acc[cb] = __builtin_amdgcn_mfma_f32_16x16x32_f16(A0, bl0, acc[cb], 0, 0, 0);
            acc[cb] = __builtin_amdgcn_mfma_f32_16x16x32_f16(A1, bl1, acc[cb], 0, 0, 0);
        }
        float zp[4] = {0.f, 0.f, 0.f, 0.f};
        #pragma unroll
        for (int cb = 0; cb < 8; ++cb) {
            int colg = cb * 16 + mm;
            float bb1 = b1[colg], vv = v[colg];
            #pragma unroll
            for (int rr = 0; rr < 4; ++rr) {
                float h = acc[cb][rr] + bb1;
                h = fmaxf(h, 0.f);
                zp[rr] += h * vv;
            }
        }
        #pragma unroll
        for (int off = 1; off < 16; off <<= 1) {
            #pragma unroll
            for (int rr = 0; rr < 4; ++rr) zp[rr] += __shfl_xor(zp[rr], off, 64);
        }
        if (mm == 0) {
            int nb = st * 16 + kq * 4;
            #pragma unroll
            for (int rr = 0; rr < 4; ++rr)
                if (nb + rr < nlocal)
                    zz[node0 + nb + rr] = dinv[node0 + nb + rr] * zp[rr];
        }
    }
}

// Layer 2 (collapsed): per-bucket zz gather (zz = 400KB L2-resident, unsorted
// csr fine) + native int LDS accumulate. out[i]=c+dinv[i]*(zz[i]+sum zz[s]).
__global__ __launch_bounds__(256) void out_kernel(
    const int* __restrict__ bcur, const unsigned int* __restrict__ csr,
    const float* __restrict__ dinv, const float* __restrict__ zz,
    const float* __restrict__ c, float* __restrict__ out, int n) {
    __shared__ int acc2[BNODES];
    int b = blockIdx.x, t = threadIdx.x;
    int node0 = b << BSHIFT;
    int nlocal = min(BNODES, n - node0);
    int base = b * SCAP;
    int cnt = bcur[b];
    if (cnt > SCAP) cnt = SCAP;
    if (t < BNODES) acc2[t] = 0;
    __syncthreads();
    for (int idx = t; idx < cnt; idx += 256) {
        unsigned int e = csr[base + idx];
        float z = zz[e >> BSHIFT];
        atomicAdd(&acc2[e & (BNODES - 1)], __float2int_rn(z * ZSCALE));
    }
    __syncthreads();
    if (t < nlocal) {
        int node = node0 + t;
        out[node] = c[0] + dinv[node] * ((float)acc2[t] * ZINV + zz[node]);
    }
}

extern "C" void kernel_launch(void* const* d_in, const int* in_sizes, int n_in,
                              void* d_out, int out_size, void* d_ws, size_t ws_size,
                              hipStream_t stream) {
    const float* x  = (const float*)d_in[0];
    const int*   ei = (const int*)d_in[1];
    const float* W1 = (const float*)d_in[2];
    const float* b1 = (const float*)d_in[3];
    const float* W2 = (const float*)d_in[4];
    const float* b2 = (const float*)d_in[5];
    const float* Wl = (const float*)d_in[6];
    const float* bl = (const float*)d_in[7];
    float* out = (float*)d_out;

    int E = in_sizes[1] / 2;
    const int* src = ei;
    const int* dst = ei + E;

    float* ws      = (float*)d_ws;
    int*   bcur    = (int*)ws;                  // 1024
    float* dinv    = (float*)(bcur + NB_PAD);   // 100000
    float* zz      = dinv + N_NODES;            // 100000
    float* v       = zz + N_NODES;              // 128
    float* c       = v + HID;                   // 4
    int*   csr     = (int*)(c + 4);             // NBUCKETS*SCAP = 2001920 ints
    uint4* Wpk     = (uint4*)(csr + (size_t)NBUCKETS * SCAP);  // 2048 uint4
    short* y       = (short*)((float*)Wpk + 8192);  // (N+4)*64 int16

    int nchunks = (E + ACHUNK - 1) / ACHUNK;   // 782

    hipMemsetAsync(bcur, 0, NB_PAD * sizeof(int), stream);
    partA_kernel<<<nchunks + 9, 256, 0, stream>>>(
        src, dst, bcur, (unsigned int*)csr, E, nchunks,
        W1, W2, b2, Wl, bl, v, c, Wpk, (int*)(y + (size_t)ZROW * 64));
    partB_kernel<<<NBUCKETS, 256, 0, stream>>>(
        bcur, (const unsigned int*)csr, dinv, (const float4*)x, (uint2*)y, N_NODES);
    fused1_kernel<<<NBUCKETS, 256, 0, stream>>>(
        (const int4*)y, (const short*)y, (const unsigned int*)csr,
        bcur, dinv, Wpk, b1, v, zz, N_NODES);
    out_kernel<<<NBUCKETS, 256, 0, stream>>>(
        bcur, (const unsigned int*)csr, dinv, zz, c, out, N_NODES);
}

// Round 13
// 181.031 us; speedup vs baseline: 1.3439x; 1.1033x over previous
//
#include <hip/hip_runtime.h>
#include <hip/hip_fp16.h>

// GCN 2-layer, N=100000, F=64, H=128, O=100, out [N,1] fp32.
// out = agg(relu(agg(x)@W1 + b1) . (W2@Wl)) + (b2@Wl + bl)
// r13: two-pass radix bucketing with LONG WRITE RUNS + unsorted high-occ fused1.
//  - Short scattered write runs = 64B-granule HBM amplification (r6: 85us,
//    r12 partA: ~80us). Fix: A1 splits E into 25 super-regions (runs ~164
//    edges = 656B); A2 splits super slices into 64 buckets (runs ~64 = 256B).
//  - Tile sort DELETED everywhere: fused1 duration = max(~125K-cycle per-edge
//    floor, FETCH/rate); rate ~2.5TB/s at r8's 48% occupancy, so unsorted
//    (fetch ~140-160MB) costs only ~55-62us — cheaper than any sort pass.
//  - fused1/out/partB = r8's proven BNODES=64 kernels (occ 48%, 19.7KB LDS).
//  - A1 buffer aliases the y region (A2 consumes it before partB writes y).
// Invariants: fp32 LDS atomicAdd = ~440cyc CAS (r1-r3) -> int fixed-point
// ds_add everywhere; (tile,dl) sorting -> same-address atomics (r9, never).

#define N_NODES 100000
#define F_IN 64
#define HID 128
#define OUT2 100
#define BSHIFT 6
#define BNODES 64
#define NBUCKETS ((N_NODES + BNODES - 1) / BNODES)  // 1563
#define SCAP 1408    // bucket capacity: mean 1024 + 12 sigma
#define NSUPER 25    // super = dst >> 12 (4096 nodes = 64 buckets each)
#define SSHIFT 12
#define SSCAP 66560  // super capacity: mean 64000 + ~10 sigma
#define SBKT 64      // buckets per super
#define ACH 4096     // edges per A1/A2 block round
#define NB_PAD 2048
#define SENTE 0xFFFFFFFFu
#define RSTRIDE 77   // acci ints per node row
#define ZROW N_NODES           // zero y-row for invalid gather slots
#define YSCALE 4096.0f         // y int16 fixed-point 2^12
#define YINV   (1.0f / 4096.0f)
#define ZSCALE 8192.0f         // zz accumulation fixed-point 2^13
#define ZINV   (1.0f / 8192.0f)

typedef _Float16 half8 __attribute__((ext_vector_type(8)));
typedef float f32x4 __attribute__((ext_vector_type(4)));

static __device__ __forceinline__ half8 as_half8(uint4 u) {
    union { uint4 u; half8 h; } x; x.u = u; return x.h;
}

// A1 (+prep): multisplit edges into 25 padded super-regions.
// Entry = src<<12 | bucket_local<<6 | dl (29 bits). Runs ~164 edges = 656B.
// scur = per-super COUNTS (memset 0); reserve = s*SSCAP + atomicAdd(count).
__global__ __launch_bounds__(256) void a1_kernel(
    const int* __restrict__ src, const int* __restrict__ dst,
    int* __restrict__ scur, unsigned int* __restrict__ sbuf1, int E, int nchunks,
    const float* __restrict__ W1, const float* __restrict__ W2,
    const float* __restrict__ b2, const float* __restrict__ Wl,
    const float* __restrict__ bl,
    float* __restrict__ v, float* __restrict__ c, uint4* __restrict__ Wpk,
    int* __restrict__ yzero) {
    int t = threadIdx.x;
    if ((int)blockIdx.x >= nchunks) {
        int pb = (int)blockIdx.x - nchunks;
        if (pb < 8) {
            // Wpk idx: bit10 = part (0=hi,1=lo), bits9..7 = cb, bit6 = kf, bits5..0 = lane
            int idx = pb * 256 + t;
            int lane2 = idx & 63;
            int kf    = (idx >> 6) & 1;
            int cb    = (idx >> 7) & 7;
            int part  = (idx >> 10) & 1;
            union { uint4 u; unsigned short s[8]; } pk;
            #pragma unroll
            for (int j = 0; j < 8; ++j) {
                int k    = kf * 32 + (lane2 >> 4) * 8 + j;
                int colg = cb * 16 + (lane2 & 15);
                float w = W1[k * HID + colg];
                __half h = __float2half_rn(w);
                if (part) h = __float2half_rn(w - __half2float(h));
                pk.s[j] = __half_as_ushort(h);
            }
            Wpk[idx] = pk.u;
        } else {
            if (t < HID) {
                float acc = 0.f;
                for (int k = 0; k < OUT2; ++k) acc += W2[t * OUT2 + k] * Wl[k];
                v[t] = acc;
            } else if (t == HID) {
                float acc = bl[0];
                for (int k = 0; k < OUT2; ++k) acc += b2[k] * Wl[k];
                *c = acc;
            }
            if (t < 128) yzero[t] = 0;   // zero rows (int16) at y[N..]
        }
        return;
    }
    __shared__ unsigned int stage[ACH];        // 16 KB
    __shared__ unsigned char sb[ACH];          // 4 KB
    __shared__ int hist[32], lo[32], gbase[32], cnt2[32];
    int base = blockIdx.x * ACH;
    int total = E - base; if (total > ACH) total = ACH;

    if (t < 32) { hist[t] = 0; cnt2[t] = 0; }
    __syncthreads();

    unsigned int pe[16];
    int bk[16];
    #pragma unroll
    for (int k = 0; k < 16; ++k) {
        int e = base + k * 256 + t;
        if (e < E) {
            int s = src[e], d = dst[e];
            pe[k] = ((unsigned int)s << 12) |
                    ((unsigned int)((d >> BSHIFT) & 63) << 6) |
                    (unsigned int)(d & 63);
            bk[k] = d >> SSHIFT;               // 0..24
            atomicAdd(&hist[bk[k]], 1);
        } else {
            bk[k] = -1;
        }
    }
    __syncthreads();
    if (t == 0) {
        int run = 0;
        #pragma unroll
        for (int i = 0; i < NSUPER; ++i) { lo[i] = run; run += hist[i]; }
    }
    __syncthreads();
    if (t < NSUPER && hist[t] > 0)
        gbase[t] = t * SSCAP + atomicAdd(&scur[t], hist[t]);
    __syncthreads();
    #pragma unroll
    for (int k = 0; k < 16; ++k) {
        if (bk[k] >= 0) {
            int b = bk[k];
            int pos = lo[b] + atomicAdd(&cnt2[b], 1);
            stage[pos] = pe[k];
            sb[pos] = (unsigned char)b;
        }
    }
    __syncthreads();
    #pragma unroll
    for (int k = 0; k < 16; ++k) {
        int idx = k * 256 + t;
        if (idx < total) {
            int b = sb[idx];
            sbuf1[gbase[b] + (idx - lo[b])] = stage[idx];  // runs ~164 edges
        }
    }
}

// A2: split each super's slice into its 64 buckets. Runs ~64 edges = 256B.
// bcur = per-bucket COUNTS (memset 0); reserve = bucket*SCAP + atomicAdd.
// csr entry = src<<6 | dl.
__global__ __launch_bounds__(256) void a2_kernel(
    const int* __restrict__ scur, const unsigned int* __restrict__ sbuf1,
    int* __restrict__ bcur, unsigned int* __restrict__ csr) {
    __shared__ unsigned int stage[ACH];        // 16 KB
    __shared__ unsigned char sb[ACH];          // 4 KB
    __shared__ int hist[SBKT], lo[SBKT], gbase[SBKT], cnt2[SBKT];
    int t = threadIdx.x;
    int sblk = blockIdx.x / 17;
    int j = blockIdx.x % 17;
    int cnt = scur[sblk]; if (cnt > SSCAP) cnt = SSCAP;
    int start = j * ACH;
    if (start >= cnt) return;
    int total = cnt - start; if (total > ACH) total = ACH;
    const unsigned int* sp = sbuf1 + (size_t)sblk * SSCAP + start;

    if (t < SBKT) { hist[t] = 0; cnt2[t] = 0; }
    __syncthreads();

    unsigned int pe[16];
    int bk[16];
    #pragma unroll
    for (int k = 0; k < 16; ++k) {
        int idx = k * 256 + t;
        if (idx < total) {
            unsigned int w = sp[idx];
            pe[k] = ((w >> 12) << 6) | (w & 63u);   // src<<6|dl
            bk[k] = (int)((w >> 6) & 63u);          // bucket_local
            atomicAdd(&hist[bk[k]], 1);
        } else {
            bk[k] = -1;
        }
    }
    __syncthreads();
    if (t == 0) {
        int run = 0;
        #pragma unroll
        for (int i = 0; i < SBKT; ++i) { lo[i] = run; run += hist[i]; }
    }
    __syncthreads();
    if (t < SBKT && hist[t] > 0) {
        int bucket = sblk * SBKT + t;
        if (bucket < NBUCKETS)
            gbase[t] = bucket * SCAP + atomicAdd(&bcur[bucket], hist[t]);
    }
    __syncthreads();
    #pragma unroll
    for (int k = 0; k < 16; ++k) {
        if (bk[k] >= 0) {
            int b = bk[k];
            int pos = lo[b] + atomicAdd(&cnt2[b], 1);
            stage[pos] = pe[k];
            sb[pos] = (unsigned char)b;
        }
    }
    __syncthreads();
    #pragma unroll
    for (int k = 0; k < 16; ++k) {
        int idx = k * 256 + t;
        if (idx < total) {
            int b = sb[idx];
            csr[gbase[b] + (idx - lo[b])] = stage[idx];   // runs ~64 edges
        }
    }
}

// Pass B: per bucket: dl-histogram -> dinv; int16 (2^12) pre-scaled y rows.
__global__ __launch_bounds__(256) void partB_kernel(
    const int* __restrict__ bcur, const unsigned int* __restrict__ csr,
    float* __restrict__ dinv,
    const float4* __restrict__ x4, uint2* __restrict__ y2, int n) {
    __shared__ int lcnt[BNODES];
    __shared__ float sdinv[BNODES];
    int b = blockIdx.x, t = threadIdx.x;
    int node0 = b << BSHIFT;
    int nlocal = min(BNODES, n - node0);
    int base = b * SCAP;
    int cnt = bcur[b];
    if (cnt > SCAP) cnt = SCAP;
    if (t < BNODES) lcnt[t] = 0;
    __syncthreads();
    for (int idx = t; idx < cnt; idx += 256)
        atomicAdd(&lcnt[csr[base + idx] & (BNODES - 1)], 1);
    __syncthreads();
    if (t < BNODES) {
        float sd = rsqrtf((float)lcnt[t] + 1.0f);
        sdinv[t] = sd;
        if (t < nlocal) dinv[node0 + t] = sd;
    }
    __syncthreads();
    for (int i = t; i < nlocal * 16; i += 256) {
        int nl = i >> 4;
        int gi = (node0 + nl) * 16 + (i & 15);
        float sc = sdinv[nl] * YSCALE;
        float4 xv = x4[gi];
        int a0 = __float2int_rn(xv.x * sc);
        int a1 = __float2int_rn(xv.y * sc);
        int a2 = __float2int_rn(xv.z * sc);
        int a3 = __float2int_rn(xv.w * sc);
        uint2 pk;
        pk.x = ((unsigned int)a0 & 0xFFFFu) | ((unsigned int)a1 << 16);
        pk.y = ((unsigned int)a2 & 0xFFFFu) | ((unsigned int)a3 << 16);
        y2[gi] = pk;
    }
}

// Fused layer 1 (r8's proven high-occupancy kernel, unsorted csr):
// block = bucket (64 dst nodes), 1563 blocks (~6/CU, occ ~48%). 8-edge x
// 8-int4-col gather, 1-deep csr prefetch; invalid slots read zero-row y[N];
// int16 sext -> native ds_add_u32 into stride-77 acci. MFMA + fused epi.
#define F1_ISSUE(EE, U, DL)                                            \
    _Pragma("unroll")                                                  \
    for (int g = 0; g < 8; ++g) {                                      \
        unsigned int e_ = __shfl((EE), g * 8 + q, 64);                 \
        int srow_ = (e_ != SENTE) ? (int)(e_ >> BSHIFT) : ZROW;        \
        DL[g] = (int)(e_ & (BNODES - 1));                              \
        U[g] = y4[srow_ * 8 + col];                                    \
    }

#define F1_CONSUME(U, DL)                                              \
    _Pragma("unroll")                                                  \
    for (int g = 0; g < 8; ++g) {                                      \
        int* rowp_ = &acci[DL[g] * RSTRIDE + col * 9];                 \
        const int* up_ = (const int*)&U[g];                            \
        _Pragma("unroll")                                              \
        for (int j = 0; j < 4; ++j) {                                  \
            int d_ = up_[j];                                           \
            atomicAdd(&rowp_[2 * j],     (d_ << 16) >> 16);            \
            atomicAdd(&rowp_[2 * j + 1], d_ >> 16);                    \
        }                                                              \
    }

__global__ __launch_bounds__(256, 6) void fused1_kernel(
    const int4* __restrict__ y4, const short* __restrict__ yh,
    const unsigned int* __restrict__ csr, const int* __restrict__ bcur,
    const float* __restrict__ dinv, const uint4* __restrict__ Wpk,
    const float* __restrict__ b1, const float* __restrict__ v,
    float* __restrict__ zz, int n) {
    __shared__ int acci[BNODES * RSTRIDE];   // 19712 B -> up to 8 blocks/CU
    int t = threadIdx.x;
    int lane = t & 63, wave = t >> 6;
    int q = lane >> 3, col = lane & 7;
    int b = blockIdx.x;
    int node0 = b << BSHIFT;
    int nlocal = min(BNODES, n - node0);
    int base = b * SCAP;
    int cnt = bcur[b];
    if (cnt > SCAP) cnt = SCAP;

    // self-loop init: acc[r][f] = y[node0+r][f] (int16, already dinv-prescaled)
    for (int r = wave; r < BNODES; r += 4) {
        int vv = 0;
        if (r < nlocal) vv = (int)yh[(node0 + r) * 64 + lane];
        acci[r * RSTRIDE + q * 9 + col] = vv;
    }
    __syncthreads();

    // 1-deep pipelined edge accumulation (waves interleave 64-edge chunks).
    int nr = (cnt + 255) >> 8;
    int lpos = wave * 64 + lane;
    unsigned int ee = (lpos < cnt) ? csr[base + lpos] : SENTE;
    for (int r = 0; r < nr; ++r) {
        int pn = lpos + (r + 1) * 256;
        unsigned int een = (pn < cnt) ? csr[base + pn] : SENTE;
        int4 u[8]; int dl[8];
        F1_ISSUE(ee, u, dl);
        F1_CONSUME(u, dl);
        ee = een;
    }
    __syncthreads();

    // MFMA + epilogue: wave handles its one 16-node sub-tile.
    int mm = lane & 15, kq = lane >> 4;
    int st = wave;
    int row = st * 16 + mm;
    float dis = ((row < nlocal) ? dinv[node0 + row] : 0.f) * YINV;
    const int* ap = &acci[row * RSTRIDE];
    half8 A0, A1;
    #pragma unroll
    for (int j = 0; j < 8; ++j) {
        A0[j] = (_Float16)(dis * (float)ap[kq * 9 + j]);
        A1[j] = (_Float16)(dis * (float)ap[(4 + kq) * 9 + j]);
    }
    f32x4 acc[8];
    #pragma unroll
    for (int cb = 0; cb < 8; ++cb) acc[cb] = (f32x4){0.f, 0.f, 0.f, 0.f};
    #pragma unroll
    for (int cb = 0; cb < 8; ++cb) {
        half8 bh0 = as_half8(Wpk[(cb * 2 + 0) * 64 + lane]);
        half8 bh1 = as_half8(Wpk[(cb * 2 + 1) * 64 + lane]);
        half8 bl0 = as_half8(Wpk[1024 + (cb * 2 + 0) * 64 + lane]);
        half8 bl1 = as_half8(Wpk[1024 + (cb * 2 + 1) * 64 + lane]);
        acc[cb] = __builtin_amdgcn_mfma_f32_16x16x32_f16(A0, bh0, acc[cb], 0, 0, 0);
        acc[cb] = __builtin_amdgcn_mfma_f32_16x16x32_f16(A1, bh1, acc[cb], 0, 0, 0);
        acc[cb] = __builtin_amdgcn_mfma_f32_16x16x32_f16(A0, bl0, acc[cb], 0, 0, 0);
        acc[cb] = __builtin_amdgcn_mfma_f32_16x16x32_f16(A1, bl1, acc[cb], 0, 0, 0);
    }
    float zp[4] = {0.f, 0.f, 0.f, 0.f};
    #pragma unroll
    for (int cb = 0; cb < 8; ++cb) {
        int colg = cb * 16 + mm;
        float bb1 = b1[colg], vv = v[colg];
        #pragma unroll
        for (int rr = 0; rr < 4; ++rr) {
            float h = acc[cb][rr] + bb1;
            h = fmaxf(h, 0.f);
            zp[rr] += h * vv;
        }
    }
    #pragma unroll
    for (int off = 1; off < 16; off <<= 1) {
        #pragma unroll
        for (int rr = 0; rr < 4; ++rr) zp[rr] += __shfl_xor(zp[rr], off, 64);
    }
    if (mm == 0) {
        int nb = st * 16 + kq * 4;
        #pragma unroll
        for (int rr = 0; rr < 4; ++rr)
            if (nb + rr < nlocal)
                zz[node0 + nb + rr] = dinv[node0 + nb + rr] * zp[rr];
    }
}

// Layer 2 (collapsed): per-bucket zz gather (zz = 400KB L2-resident) +
// native int LDS accumulate. out[i] = c + dinv[i]*(zz[i] + sum_in zz[s]).
__global__ __launch_bounds__(256) void out_kernel(
    const int* __restrict__ bcur, const unsigned int* __restrict__ csr,
    const float* __restrict__ dinv, const float* __restrict__ zz,
    const float* __restrict__ c, float* __restrict__ out, int n) {
    __shared__ int acc2[BNODES];
    int b = blockIdx.x, t = threadIdx.x;
    int node0 = b << BSHIFT;
    int nlocal = min(BNODES, n - node0);
    int base = b * SCAP;
    int cnt = bcur[b];
    if (cnt > SCAP) cnt = SCAP;
    if (t < BNODES) acc2[t] = 0;
    __syncthreads();
    for (int idx = t; idx < cnt; idx += 256) {
        unsigned int e = csr[base + idx];
        float z = zz[e >> BSHIFT];
        atomicAdd(&acc2[e & (BNODES - 1)], __float2int_rn(z * ZSCALE));
    }
    __syncthreads();
    if (t < nlocal) {
        int node = node0 + t;
        out[node] = c[0] + dinv[node] * ((float)acc2[t] * ZINV + zz[node]);
    }
}

extern "C" void kernel_launch(void* const* d_in, const int* in_sizes, int n_in,
                              void* d_out, int out_size, void* d_ws, size_t ws_size,
                              hipStream_t stream) {
    const float* x  = (const float*)d_in[0];
    const int*   ei = (const int*)d_in[1];
    const float* W1 = (const float*)d_in[2];
    const float* b1 = (const float*)d_in[3];
    const float* W2 = (const float*)d_in[4];
    const float* b2 = (const float*)d_in[5];
    const float* Wl = (const float*)d_in[6];
    const float* bl = (const float*)d_in[7];
    float* out = (float*)d_out;

    int E = in_sizes[1] / 2;
    const int* src = ei;
    const int* dst = ei + E;

    float* ws      = (float*)d_ws;
    int*   scur    = (int*)ws;                  // 32 (25 used)
    int*   bcur    = scur + 32;                 // 2048 (1563 used)
    float* dinv    = (float*)(bcur + NB_PAD);   // 100000
    float* zz      = dinv + N_NODES;            // 100000
    float* v       = zz + N_NODES;              // 128
    float* c       = v + HID;                   // 4
    int*   csr     = (int*)(c + 4);             // NBUCKETS*SCAP = 2200704 ints
    uint4* Wpk     = (uint4*)(csr + (size_t)NBUCKETS * SCAP);  // 2048 uint4
    short* y       = (short*)((float*)Wpk + 8192);  // (N+4)*64 int16 = 12.8MB
    // A1 super-buffer aliases the y region (consumed by A2 before y is written)
    unsigned int* sbuf1 = (unsigned int*)y;     // 25*66560 ints = 6.66MB < 12.8MB

    int nchunks = (E + ACH - 1) / ACH;          // 391

    hipMemsetAsync(scur, 0, (32 + NB_PAD) * sizeof(int), stream);
    a1_kernel<<<nchunks + 9, 256, 0, stream>>>(
        src, dst, scur, sbuf1, E, nchunks,
        W1, W2, b2, Wl, bl, v, c, Wpk, (int*)(y + (size_t)ZROW * 64));
    a2_kernel<<<NSUPER * 17, 256, 0, stream>>>(
        scur, sbuf1, bcur, (unsigned int*)csr);
    partB_kernel<<<NBUCKETS, 256, 0, stream>>>(
        bcur, (const unsigned int*)csr, dinv, (const float4*)x, (uint2*)y, N_NODES);
    fused1_kernel<<<NBUCKETS, 256, 0, stream>>>(
        (const int4*)y, (const short*)y, (const unsigned int*)csr,
        bcur, dinv, Wpk, b1, v, zz, N_NODES);
    out_kernel<<<NBUCKETS, 256, 0, stream>>>(
        bcur, (const unsigned int*)csr, dinv, zz, c, out, N_NODES);
}